// Round 16
// baseline (159.943 us; speedup 1.0000x reference)
//
#include <hip/hip_runtime.h>
#include <math.h>

#define NP 4
#define NN 8192
#define NM 8192

// ws layout (float units):
//   QA: cad_t queries dup-negated {-x,-x,-y,-y,-z,-z,h,h}  262144 @ 0
//   QB: cam  queries dup-negated                           262144 @ 262144
//   TA: cad_t targets float4 (x,y,z,h)                     131072 @ 524288
//   TB: cam  targets float4                                131072 @ 655360
//   PART: [2 dir][16 qslice][32768] partial mins           1048576 @ 786432
#define QA_OFF 0
#define QB_OFF 262144
#define TA_OFF 524288
#define TB_OFF 655360
#define PART_OFF 786432
// total 1,835,008 floats = 7.34 MB

#define TT 8        // lane-owned targets (outputs) per thread
#define QSPLIT 16   // query chunks -> PART slice count
#define QCHUNK 512  // queries per chunk (8192/QSPLIT)
// grid (4, QSPLIT, 8): block = 4 waves, wave w owns target slab bx*4+w
// (512 targets each); z = dir*4+... -> dir = z&1, part = z>>1. 512 blocks.

typedef float float2v __attribute__((ext_vector_type(2)));

__device__ inline float2v pk_fma(float2v a, float2v b, float2v c) {
    float2v d;
    asm("v_pk_fma_f32 %0, %1, %2, %3" : "=v"(d) : "v"(a), "v"(b), "v"(c));
    return d;
}

__device__ inline void make_transform(const float* __restrict__ quat,
                                      const float* __restrict__ tra,
                                      int p, float T[12]) {
    float q0 = quat[p * 4 + 0], q1 = quat[p * 4 + 1];
    float q2 = quat[p * 4 + 2], q3 = quat[p * 4 + 3];
    float inv = 1.0f / sqrtf(q0 * q0 + q1 * q1 + q2 * q2 + q3 * q3);
    float a = q0 * inv, b = q1 * inv, c = q2 * inv, d = q3 * inv;
    T[0] = 1.0f - 2.0f * c * c - 2.0f * d * d;
    T[1] = 2.0f * b * c - 2.0f * a * d;
    T[2] = 2.0f * a * c + 2.0f * b * d;
    T[3] = tra[p * 3 + 0];
    T[4] = 2.0f * b * c + 2.0f * a * d;
    T[5] = 1.0f - 2.0f * b * b - 2.0f * d * d;
    T[6] = 2.0f * c * d - 2.0f * a * b;
    T[7] = tra[p * 3 + 1];
    T[8] = 2.0f * b * d - 2.0f * a * c;
    T[9] = 2.0f * a * b + 2.0f * c * d;
    T[10] = 1.0f - 2.0f * b * b - 2.0f * c * c;
    T[11] = tra[p * 3 + 2];
}

// 256 blocks x 256 threads over 65536 points: emit both layouts per cloud,
// plus transforms -> out[1..64] and out[0] = 0.
__global__ __launch_bounds__(256) void prep_kernel(
    const float* __restrict__ cam, const float* __restrict__ cad,
    const float* __restrict__ quat, const float* __restrict__ tra,
    float* __restrict__ ws, float* __restrict__ out) {
    int idx = blockIdx.x * 256 + threadIdx.x;  // [0, 65536)

    float vx, vy, vz;
    int qoff, toff, local;
    if (idx < NP * NM) {
        int p = idx >> 13;
        float T[12];
        make_transform(quat, tra, p, T);
        float x = cad[idx * 3 + 0];
        float y = cad[idx * 3 + 1];
        float z = cad[idx * 3 + 2];
        vx = fmaf(T[0], x, fmaf(T[1], y, fmaf(T[2], z, T[3])));
        vy = fmaf(T[4], x, fmaf(T[5], y, fmaf(T[6], z, T[7])));
        vz = fmaf(T[8], x, fmaf(T[9], y, fmaf(T[10], z, T[11])));
        qoff = QA_OFF; toff = TA_OFF; local = idx;
    } else {
        local = idx - NP * NM;
        vx = cam[local * 3 + 0];
        vy = cam[local * 3 + 1];
        vz = cam[local * 3 + 2];
        qoff = QB_OFF; toff = TB_OFF;
    }
    float h = 0.5f * (vx * vx + vy * vy + vz * vz);
    float* q = ws + qoff + (size_t)local * 8;
    q[0] = -vx; q[1] = -vx;
    q[2] = -vy; q[3] = -vy;
    q[4] = -vz; q[5] = -vz;
    q[6] = h;   q[7] = h;
    ((float4*)(ws + toff))[local] = make_float4(vx, vy, vz, h);

    if (idx < 64) {
        int p2 = idx >> 4;
        int r = (idx >> 2) & 3;
        int c = idx & 3;
        float T[12];
        make_transform(quat, tra, p2, T);
        float v;
        if (r == 3)
            v = (c == 3) ? 1.0f : 0.0f;
        else
            v = T[r * 4 + c];
        out[1 + idx] = v;
    } else if (idx == 64) {
        out[0] = 0.0f;
    }
}

// Dual-pass streaming chamfer. Wave-private work, NO LDS, NO barriers,
// NO atomics, NO cross-lane reduction:
//   lanes own 8 output points (x,y,z,h in regs, pk-paired);
//   the min-dimension streams as WAVE-UNIFORM queries {-x,-x,...,h,h}
//   read via uniform index -> s_load (SMEM pipe) -> SGPR operand of
//   v_pk_fma_f32. Per 2 pairs: 3 pk_fma + 2 v_min = 2.5 inst.
//   u = h_q - q.t accumulates from sH; running per-lane min; h_t added at
//   the (coalesced, unique-writer) partial store.
__global__ __launch_bounds__(256) void chamfer_kernel(
    const float* __restrict__ ws, float* __restrict__ part) {
    int tid = threadIdx.x;
    int lane = tid & 63;
    int w = tid >> 6;
    int dir = blockIdx.z & 1;    // 0: outputs=cad (stream cam), 1: outputs=cam
    int p = blockIdx.z >> 1;
    int qs = blockIdx.y;         // query chunk -> PART slice
    int slab = blockIdx.x * 4 + w;  // 16 slabs of 512 targets per dir-part
    const float INF = __uint_as_float(0x7f800000u);

    const float4* T = (const float4*)(ws + (dir == 0 ? TA_OFF : TB_OFF)) + p * 8192;
    const float2v* Q = (const float2v*)(ws + (dir == 0 ? QB_OFF : QA_OFF)) + (size_t)p * 8192 * 4;

    int tbase = slab * 512;
    float2v TX[TT / 2], TY[TT / 2], TZ[TT / 2], TH[TT / 2], mB[TT / 2];
#pragma unroll
    for (int j = 0; j < TT; ++j) {
        float4 t = T[tbase + j * 64 + lane];
        TX[j >> 1][j & 1] = t.x;
        TY[j >> 1][j & 1] = t.y;
        TZ[j >> 1][j & 1] = t.z;
        TH[j >> 1][j & 1] = t.w;
        mB[j >> 1][j & 1] = INF;
    }

    const float2v* qp = Q + (size_t)(qs * QCHUNK) * 4;
#pragma unroll 4
    for (int qi = 0; qi < QCHUNK; ++qi) {
        float2v sX = qp[qi * 4 + 0];
        float2v sY = qp[qi * 4 + 1];
        float2v sZ = qp[qi * 4 + 2];
        float2v sH = qp[qi * 4 + 3];
#pragma unroll
        for (int i = 0; i < TT / 2; ++i) {
            float2v u = pk_fma(TZ[i], sZ, sH);
            u = pk_fma(TY[i], sY, u);
            u = pk_fma(TX[i], sX, u);
            mB[i][0] = fminf(mB[i][0], u[0]);
            mB[i][1] = fminf(mB[i][1], u[1]);
        }
    }

    // store d^2/2 = min_u + h_t to private slice PART[dir][qs][p*8192 + n]
    float* dst = part + ((size_t)dir * QSPLIT + qs) * 32768 + p * 8192;
#pragma unroll
    for (int j = 0; j < TT; ++j) {
        dst[tbase + j * 64 + lane] = mB[j >> 1][j & 1] + TH[j >> 1][j & 1];
    }
}

// 128 blocks x 256: merge the 16 slices of each direction, sqrt, weight.
__global__ __launch_bounds__(256) void finalize_kernel(
    const float* __restrict__ ws, const float* __restrict__ w,
    float* __restrict__ out) {
    const float* part = ws + PART_OFF;
    int i = blockIdx.x * 256 + threadIdx.x;  // [0, 32768)
    int tid = threadIdx.x;
    const float INF = __uint_as_float(0x7f800000u);

    float va = INF, vb = INF;
#pragma unroll 8
    for (int s = 0; s < QSPLIT; ++s) {
        va = fminf(va, part[(size_t)s * 32768 + i]);
        vb = fminf(vb, part[((size_t)QSPLIT + s) * 32768 + i]);
    }

    float wp = w[(i >> 13) & 3];
    float acc = wp * (sqrtf(fmaxf(2.0f * va, 0.0f)) +
                      sqrtf(fmaxf(2.0f * vb, 0.0f)));

#pragma unroll
    for (int off = 32; off > 0; off >>= 1) acc += __shfl_down(acc, off, 64);

    __shared__ float wsum[4];
    if ((tid & 63) == 0) wsum[tid >> 6] = acc;
    __syncthreads();
    if (tid == 0) {
        float blocksum = (wsum[0] + wsum[1] + wsum[2] + wsum[3]) * (1.0f / 8192.0f);
        atomicAdd(out, blocksum);
    }
}

extern "C" void kernel_launch(void* const* d_in, const int* in_sizes, int n_in,
                              void* d_out, int out_size, void* d_ws, size_t ws_size,
                              hipStream_t stream) {
    const float* cam = (const float*)d_in[0];   // (P, N, 3)
    const float* cad = (const float*)d_in[1];   // (P, M, 3)
    const float* w = (const float*)d_in[2];     // (P,)
    const float* quat = (const float*)d_in[3];  // (P, 4)
    const float* tra = (const float*)d_in[4];   // (P, 3, 1)
    float* out = (float*)d_out;
    float* ws = (float*)d_ws;

    prep_kernel<<<256, 256, 0, stream>>>(cam, cad, quat, tra, ws, out);

    dim3 grid(4, QSPLIT, 2 * NP);
    chamfer_kernel<<<grid, 256, 0, stream>>>(ws, ws + PART_OFF);

    finalize_kernel<<<128, 256, 0, stream>>>(ws, w, out);
}

// Round 17
// 106.268 us; speedup vs baseline: 1.5051x; 1.5051x over previous
//
#include <hip/hip_runtime.h>
#include <math.h>

#define NP 4
#define NN 8192
#define NM 8192

// ws layout (float units):
//   PKA: cad_t packed float4 (x,y,z,h=0.5|v|^2)  131072 @ 0
//   PKB: cam packed float4                        131072 @ 131072
//   MINS: minA[32768] then minB[32768]            65536  @ 262144
#define PKA_OFF 0
#define PKB_OFF 131072
#define MINS_OFF 262144
#define MINB_REL (NP * NM)
// total 327,680 floats = 1.31 MB

#define TQ 8        // queries per thread
#define QT 2048     // queries per block (256 * TQ)
#define SPLITS 64   // target splits -> grid (4,64,8) = 2048 blocks = 8/CU
#define SPAN 128    // targets per block

typedef float float2v __attribute__((ext_vector_type(2)));

__device__ inline float min3f(float a, float b, float c) {
    float d;
    asm("v_min3_f32 %0, %1, %2, %3" : "=v"(d) : "v"(a), "v"(b), "v"(c));
    return d;
}
__device__ inline float2v pk_fma(float2v a, float2v b, float2v c) {
    float2v d;
    asm("v_pk_fma_f32 %0, %1, %2, %3" : "=v"(d) : "v"(a), "v"(b), "v"(c));
    return d;
}

__device__ inline void make_transform(const float* __restrict__ quat,
                                      const float* __restrict__ tra,
                                      int p, float T[12]) {
    float q0 = quat[p * 4 + 0], q1 = quat[p * 4 + 1];
    float q2 = quat[p * 4 + 2], q3 = quat[p * 4 + 3];
    float inv = 1.0f / sqrtf(q0 * q0 + q1 * q1 + q2 * q2 + q3 * q3);
    float a = q0 * inv, b = q1 * inv, c = q2 * inv, d = q3 * inv;
    T[0] = 1.0f - 2.0f * c * c - 2.0f * d * d;
    T[1] = 2.0f * b * c - 2.0f * a * d;
    T[2] = 2.0f * a * c + 2.0f * b * d;
    T[3] = tra[p * 3 + 0];
    T[4] = 2.0f * b * c + 2.0f * a * d;
    T[5] = 1.0f - 2.0f * b * b - 2.0f * d * d;
    T[6] = 2.0f * c * d - 2.0f * a * b;
    T[7] = tra[p * 3 + 1];
    T[8] = 2.0f * b * d - 2.0f * a * c;
    T[9] = 2.0f * a * b + 2.0f * c * d;
    T[10] = 1.0f - 2.0f * b * b - 2.0f * c * c;
    T[11] = tra[p * 3 + 2];
}

// 256 blocks x 256 threads: pack both clouds as float4 (x,y,z,h), init MINS,
// emit transforms to out[1..64], zero out[0].
__global__ __launch_bounds__(256) void prep_kernel(
    const float* __restrict__ cam, const float* __restrict__ cad,
    const float* __restrict__ quat, const float* __restrict__ tra,
    float* __restrict__ ws, float* __restrict__ out) {
    int idx = blockIdx.x * 256 + threadIdx.x;  // [0, 65536)
    const float INF = __uint_as_float(0x7f800000u);

    float vx, vy, vz;
    int pkoff, local;
    if (idx < NP * NM) {
        int p = idx >> 13;
        float T[12];
        make_transform(quat, tra, p, T);
        float x = cad[idx * 3 + 0];
        float y = cad[idx * 3 + 1];
        float z = cad[idx * 3 + 2];
        vx = fmaf(T[0], x, fmaf(T[1], y, fmaf(T[2], z, T[3])));
        vy = fmaf(T[4], x, fmaf(T[5], y, fmaf(T[6], z, T[7])));
        vz = fmaf(T[8], x, fmaf(T[9], y, fmaf(T[10], z, T[11])));
        pkoff = PKA_OFF; local = idx;
    } else {
        local = idx - NP * NM;
        vx = cam[local * 3 + 0];
        vy = cam[local * 3 + 1];
        vz = cam[local * 3 + 2];
        pkoff = PKB_OFF;
    }
    float h = 0.5f * (vx * vx + vy * vy + vz * vz);
    ((float4*)(ws + pkoff))[local] = make_float4(vx, vy, vz, h);
    ws[MINS_OFF + idx] = INF;

    if (idx < 64) {
        int p2 = idx >> 4;
        int r = (idx >> 2) & 3;
        int c = idx & 3;
        float T[12];
        make_transform(quat, tra, p2, T);
        float v;
        if (r == 3)
            v = (c == 3) ? 1.0f : 0.0f;
        else
            v = T[r * 4 + c];
        out[1 + idx] = v;
    } else if (idx == 64) {
        out[0] = 0.0f;
    }
}

// grid (4, 64, 8) = 2048 blocks = 8 blocks/CU. NO waves-per-eu cap: VGPR ~80
// allows ~6 waves/SIMD so the LDS pipe (20.5 us of ds_read traffic) overlaps
// under VALU (14 us of pk_fma) instead of summing (R13's 43.7 = sum).
// Targets staged in LDS as SoA-of-PAIRS (sX2[pp]={x0,x1}, ...): ds_read_b64
// broadcast reads, no extract-movs; per 2 targets x 8 queries: 3 pk_fma +
// 1 min3 each = 2.0 VALU inst/pair exactly.
__global__ __launch_bounds__(256) void chamfer_kernel(
    const float* __restrict__ ws, float* __restrict__ mins) {
    int tid = threadIdx.x;
    int p = blockIdx.z >> 1;
    int role = blockIdx.z & 1;

    const float4* Q;
    const float4* T;
    float* minarr;
    if (role == 0) {  // queries = cad_t, targets = cam -> minA
        Q = (const float4*)(ws + PKA_OFF) + p * NM;
        T = (const float4*)(ws + PKB_OFF) + p * NN;
        minarr = mins + p * NM;
    } else {          // queries = cam, targets = cad_t -> minB
        Q = (const float4*)(ws + PKB_OFF) + p * NN;
        T = (const float4*)(ws + PKA_OFF) + p * NM;
        minarr = mins + MINB_REL + p * NN;
    }

    __shared__ float2v sX2[SPAN / 2], sY2[SPAN / 2], sZ2[SPAN / 2],
        sH2[SPAN / 2];

    const float INF = __uint_as_float(0x7f800000u);
    int q0 = blockIdx.x * QT + tid;
    float2v nqx[TQ], nqy[TQ], nqz[TQ];
    float qw[TQ], tmin[TQ];
#pragma unroll
    for (int k = 0; k < TQ; ++k) {
        float4 v = Q[q0 + k * 256];
        nqx[k] = (float2v){-v.x, -v.x};
        nqy[k] = (float2v){-v.y, -v.y};
        nqz[k] = (float2v){-v.z, -v.z};
        qw[k] = v.w;
        tmin[k] = INF;
    }

    int tbase = blockIdx.y * SPAN;
    if (tid < SPAN) {
        float4 t = T[tbase + tid];
        int pp = tid >> 1, ln = tid & 1;
        sX2[pp][ln] = t.x;
        sY2[pp][ln] = t.y;
        sZ2[pp][ln] = t.z;
        sH2[pp][ln] = t.w;
    }
    __syncthreads();

#pragma unroll 4
    for (int pp = 0; pp < SPAN / 2; ++pp) {
        float2v X = sX2[pp];
        float2v Y = sY2[pp];
        float2v Z = sZ2[pp];
        float2v H = sH2[pp];
#pragma unroll
        for (int k = 0; k < TQ; ++k) {
            float2v u = pk_fma(nqx[k], X, pk_fma(nqy[k], Y, pk_fma(nqz[k], Z, H)));
            tmin[k] = min3f(tmin[k], u[0], u[1]);
        }
    }

#pragma unroll
    for (int k = 0; k < TQ; ++k) {
        float d2 = 2.0f * (qw[k] + tmin[k]);
        d2 = fmaxf(d2, 0.0f);
        atomicMin((unsigned int*)&minarr[q0 + k * 256], __float_as_uint(d2));
    }
}

__global__ __launch_bounds__(256) void finalize_kernel(
    const float* __restrict__ ws, const float* __restrict__ w,
    float* __restrict__ out) {
    const float* vals = ws + MINS_OFF;
    int i = blockIdx.x * 256 + threadIdx.x;  // [0, 32768)
    int tid = threadIdx.x;

    float wl[4] = {w[0], w[1], w[2], w[3]};

    int i2 = i + 32768;
    float acc = wl[(i >> 13) & 3] * sqrtf(vals[i]) +
                wl[(i2 >> 13) & 3] * sqrtf(vals[i2]);

#pragma unroll
    for (int off = 32; off > 0; off >>= 1) acc += __shfl_down(acc, off, 64);

    __shared__ float wsum[4];
    if ((tid & 63) == 0) wsum[tid >> 6] = acc;
    __syncthreads();
    if (tid == 0) {
        float blocksum = (wsum[0] + wsum[1] + wsum[2] + wsum[3]) * (1.0f / 8192.0f);
        atomicAdd(out, blocksum);
    }
}

extern "C" void kernel_launch(void* const* d_in, const int* in_sizes, int n_in,
                              void* d_out, int out_size, void* d_ws, size_t ws_size,
                              hipStream_t stream) {
    const float* cam = (const float*)d_in[0];   // (P, N, 3)
    const float* cad = (const float*)d_in[1];   // (P, M, 3)
    const float* w = (const float*)d_in[2];     // (P,)
    const float* quat = (const float*)d_in[3];  // (P, 4)
    const float* tra = (const float*)d_in[4];   // (P, 3, 1)
    float* out = (float*)d_out;
    float* ws = (float*)d_ws;

    prep_kernel<<<256, 256, 0, stream>>>(cam, cad, quat, tra, ws, out);

    dim3 grid(NM / QT, SPLITS, 2 * NP);
    chamfer_kernel<<<grid, 256, 0, stream>>>(ws, ws + MINS_OFF);

    finalize_kernel<<<128, 256, 0, stream>>>(ws, w, out);
}